// Round 5
// baseline (313.967 us; speedup 1.0000x reference)
//
#include <hip/hip_runtime.h>

#define IN_FEAT 256
#define OUT_FEAT 128

typedef __attribute__((ext_vector_type(8))) short bf16x8;
typedef __attribute__((ext_vector_type(4))) float f32x4;

static __device__ __forceinline__ unsigned short f2bf(float f) {
    union { float f; unsigned u; } v; v.f = f;
    unsigned u = v.u;
    return (unsigned short)((u + 0x7FFFu + ((u >> 16) & 1u)) >> 16);
}
static __device__ __forceinline__ float bfl(unsigned u) {
    union { unsigned u; float f; } x; x.u = u << 16; return x.f;
}
static __device__ __forceinline__ float bfh(unsigned u) {
    union { unsigned u; float f; } x; x.u = u & 0xFFFF0000u; return x.f;
}

// ---- prep: Wt[n][k] = bf16(W[k][n]), Wt is [128][256] bf16 ----
__global__ __launch_bounds__(256) void prep_wt(const float* __restrict__ W,
                                               unsigned short* __restrict__ Wt) {
    int idx = blockIdx.x * 256 + threadIdx.x;      // 0..32767
    int n = idx >> 8, k = idx & 255;
    Wt[idx] = f2bf(W[(size_t)k * OUT_FEAT + n]);
}

// ---- prep: row_ptr[i] = lower_bound(rows, i), i in [0, N] ----
__global__ __launch_bounds__(256) void rowptr_kernel(const int* __restrict__ rows,
                                                     int* __restrict__ row_ptr,
                                                     int E, int N) {
    int i = blockIdx.x * 256 + threadIdx.x;
    if (i > N) return;
    int lo = 0, hi = E;
    while (lo < hi) {
        int mid = (lo + hi) >> 1;
        if (rows[mid] < i) lo = mid + 1; else hi = mid;
    }
    row_ptr[i] = lo;
}

// ---- GEMM v4: S = bf16(X @ W). W staged in LDS in two 32KB K-halves.
// 512 thr = 8 waves; wave w owns rows m0+w*16..+16, all 128 cols.
// VGPR <= 128 (launch_bounds 512,4) -> 2 blocks/CU, no spills (8 A-loads live max).
__global__ __launch_bounds__(512, 4) void gemm_v4(const float* __restrict__ X,
                                                  const unsigned short* __restrict__ Wt,
                                                  unsigned short* __restrict__ S, int M) {
    __shared__ unsigned short Bs[128 * 128];   // 32KB: uint4 slot idx = (n<<4)|(s^(n&7))

    const int t = threadIdx.x;
    const int w = t >> 6;
    const int lane = t & 63;
    const int lr = lane & 15, lg = lane >> 4;
    const int m0 = blockIdx.x * 128;
    const int row = m0 + w * 16 + lr;
    const int crow = (row < M) ? row : (M - 1);
    const float4* xp = (const float4*)(X + (size_t)crow * IN_FEAT) + lg * 2;

    f32x4 acc[8];
#pragma unroll
    for (int ni = 0; ni < 8; ++ni) acc[ni] = (f32x4){0.f, 0.f, 0.f, 0.f};

#pragma unroll 1
    for (int h = 0; h < 2; ++h) {
        __syncthreads();                       // all reads of previous half done
        for (int i = t; i < 2048; i += 512) {  // stage 128 n-rows x 128 k (16 uint4/row)
            int r = i >> 4, s = i & 15;
            ((uint4*)Bs)[(r << 4) | (s ^ (r & 7))] = ((const uint4*)Wt)[r * 32 + h * 16 + s];
        }
        __syncthreads();

#pragma unroll
        for (int kb = 0; kb < 4; ++kb) {       // k = h*128 + kb*32 + lg*8 + 0..7
            float4 f0 = xp[h * 32 + kb * 8];
            float4 f1 = xp[h * 32 + kb * 8 + 1];
            union { uint4 u; bf16x8 v; } a;
            a.u.x = (unsigned)f2bf(f0.x) | ((unsigned)f2bf(f0.y) << 16);
            a.u.y = (unsigned)f2bf(f0.z) | ((unsigned)f2bf(f0.w) << 16);
            a.u.z = (unsigned)f2bf(f1.x) | ((unsigned)f2bf(f1.y) << 16);
            a.u.w = (unsigned)f2bf(f1.z) | ((unsigned)f2bf(f1.w) << 16);
            const int sb = kb * 4 + lg;        // k-slot 0..15 within half
#pragma unroll
            for (int ni = 0; ni < 8; ++ni) {
                int r2 = ni * 16 + lr;
                bf16x8 b = ((const bf16x8*)Bs)[(r2 << 4) | (sb ^ (r2 & 7))];
                acc[ni] = __builtin_amdgcn_mfma_f32_16x16x32_bf16(a.v, b, acc[ni], 0, 0, 0);
            }
        }
    }

    // epilogue: acc -> LDS (reuse Bs, 32KB = 128x128 bf16) -> coalesced uint4 stores
    __syncthreads();
    unsigned short* Cs = Bs + w * 16 * 128;    // wave's 16x128 bf16 panel
#pragma unroll
    for (int ni = 0; ni < 8; ++ni)
#pragma unroll
        for (int j = 0; j < 4; ++j)
            Cs[(lg * 4 + j) * 128 + ni * 16 + lr] = f2bf(acc[ni][j]);
    __syncthreads();

    const int rows_blk = (M - m0 < 128) ? (M - m0) : 128;
    for (int i = t; i < 2048; i += 512) {
        int R = i >> 4;
        if (R < rows_blk)
            ((uint4*)(S + (size_t)(m0 + R) * OUT_FEAT))[i & 15] = ((const uint4*)Bs)[i];
    }
}

// ---- SpMM v4: out[r] = sum_e vals[e] * S[cols[e]]  (S bf16 [N][128]) ----
// 4 waves/block, TWO rows per wave (lane halves). Per row: 2 edge subgroups x 4-deep batch
// = 8 edges in flight per row, 16 per wave. One shfl_xor(16) reduction.
__global__ __launch_bounds__(256) void spmm_v4(const int* __restrict__ cols,
                                               const float* __restrict__ vals,
                                               const unsigned short* __restrict__ S,
                                               const int* __restrict__ row_ptr,
                                               float* __restrict__ out, int N) {
    const int w = threadIdx.x >> 6;
    const int lane = threadIdx.x & 63;
    const int half = lane >> 5;
    const int hl = lane & 31;
    const int g = hl >> 4;                 // edge subgroup within row
    const int fb = hl & 15;                // feature block (8 bf16)
    const int r = blockIdx.x * 8 + w * 2 + half;
    if (r >= N) return;

    const int start = row_ptr[r];
    const int end   = row_ptr[r + 1];
    const int deg   = end - start;

    float acc[8] = {0.f, 0.f, 0.f, 0.f, 0.f, 0.f, 0.f, 0.f};
    const unsigned short* Sb = S + fb * 8;

    for (int off = 0; __any(off < deg); off += 8) {
        int c[4]; float v[4]; uint4 p[4];
#pragma unroll
        for (int u = 0; u < 4; ++u) {
            int e = start + off + u * 2 + g;
            bool ok = (e < end);
            int ec = ok ? e : 0;
            c[u] = cols[ec];
            v[u] = ok ? vals[ec] : 0.f;
        }
#pragma unroll
        for (int u = 0; u < 4; ++u)
            p[u] = *(const uint4*)(Sb + (size_t)c[u] * OUT_FEAT);
#pragma unroll
        for (int u = 0; u < 4; ++u) {
            float v0 = v[u];
            acc[0] += v0 * bfl(p[u].x); acc[1] += v0 * bfh(p[u].x);
            acc[2] += v0 * bfl(p[u].y); acc[3] += v0 * bfh(p[u].y);
            acc[4] += v0 * bfl(p[u].z); acc[5] += v0 * bfh(p[u].z);
            acc[6] += v0 * bfl(p[u].w); acc[7] += v0 * bfh(p[u].w);
        }
    }

#pragma unroll
    for (int j = 0; j < 8; ++j)
        acc[j] += __shfl_xor(acc[j], 16);

    if (g == 0) {
        *(float4*)(out + (size_t)r * OUT_FEAT + fb * 8) =
            make_float4(acc[0], acc[1], acc[2], acc[3]);
        *(float4*)(out + (size_t)r * OUT_FEAT + fb * 8 + 4) =
            make_float4(acc[4], acc[5], acc[6], acc[7]);
    }
}

extern "C" void kernel_launch(void* const* d_in, const int* in_sizes, int n_in,
                              void* d_out, int out_size, void* d_ws, size_t ws_size,
                              hipStream_t stream) {
    const float* X    = (const float*)d_in[0];
    const float* W    = (const float*)d_in[1];
    const int*   rows = (const int*)d_in[2];
    const int*   cols = (const int*)d_in[3];
    const float* vals = (const float*)d_in[4];
    float*       out  = (float*)d_out;

    const int M = in_sizes[0] / IN_FEAT;   // 100000
    const int E = in_sizes[2];             // 3200000

    unsigned short* S  = (unsigned short*)d_ws;               // M*128 bf16 = 25.6 MB
    unsigned short* Wt = S + (size_t)M * OUT_FEAT;            // 128*256 bf16 = 64 KB
    int* row_ptr = (int*)(Wt + IN_FEAT * OUT_FEAT);           // (M+1) ints

    prep_wt<<<(IN_FEAT * OUT_FEAT) / 256, 256, 0, stream>>>(W, Wt);
    rowptr_kernel<<<(M + 256) / 256 + 1, 256, 0, stream>>>(rows, row_ptr, E, M);
    gemm_v4<<<(M + 127) / 128, 512, 0, stream>>>(X, Wt, S, M);
    spmm_v4<<<(M + 7) / 8, 256, 0, stream>>>(cols, vals, S, row_ptr, out, M);
}